// Round 1
// baseline (185.207 us; speedup 1.0000x reference)
//
#include <hip/hip_runtime.h>
#include <hip/hip_bf16.h>
#include <stdint.h>

// Problem constants
#define Bb 8
#define Nn_ 1024
#define Cc_ 768
#define Hh 12
#define HDd 64
#define BHh 96
#define SCALE_F 0.03608439182435161f  // 768^-0.5

typedef __attribute__((ext_vector_type(4))) float f32x4;
typedef __attribute__((ext_vector_type(8))) __bf16 bf16x8;

__device__ __forceinline__ unsigned short f2bf(float f) {
  uint32_t u = __builtin_bit_cast(uint32_t, f);
  uint32_t r = (u + 0x7fffu + ((u >> 16) & 1u)) >> 16;
  return (unsigned short)r;
}

typedef const __attribute__((address_space(1))) uint32_t* gas1_t;
typedef __attribute__((address_space(3))) uint32_t* las3_t;
__device__ __forceinline__ void gl_lds16(const void* g, void* l) {
  __builtin_amdgcn_global_load_lds((gas1_t)g, (las3_t)l, 16, 0, 0);
}

// ---------------- cast x (f32 -> bf16), 4 elems/thread ----------------
__global__ void k_cvt_x(const float* __restrict__ x, unsigned short* __restrict__ xb, int n4) {
  int i = blockIdx.x * blockDim.x + threadIdx.x;
  if (i >= n4) return;
  float4 v = ((const float4*)x)[i];
  ushort4 o;
  o.x = f2bf(v.x); o.y = f2bf(v.y); o.z = f2bf(v.z); o.w = f2bf(v.w);
  ((ushort4*)xb)[i] = o;
}

// ------------- transpose f32 [R][CC] -> bf16 [CC][R] ------------------
template <int R, int CC>
__global__ void k_transpose(const float* __restrict__ src, unsigned short* __restrict__ dst) {
  __shared__ unsigned short tile[64][65];
  int c0 = blockIdx.x * 64;
  int r0 = blockIdx.y * 64;
  int t = threadIdx.x;
#pragma unroll
  for (int i = 0; i < 16; ++i) {
    int idx = t + 256 * i;
    int r = idx >> 6, c = idx & 63;
    tile[r][c] = f2bf(src[(size_t)(r0 + r) * CC + c0 + c]);
  }
  __syncthreads();
#pragma unroll
  for (int i = 0; i < 16; ++i) {
    int idx = t + 256 * i;
    int a = idx >> 6, bq = idx & 63;
    dst[(size_t)(c0 + a) * R + r0 + bq] = tile[bq][a];
  }
}

// ---------------- GEMM: A[M][K]bf16 x Bt[N][K]bf16 --------------------
// 128x128 tile, BK=64, 4 waves (2x2), each wave 64x64 = 4x4 mfma 16x16x32.
// EPI 0: out fp32 [M][N] (+bias).  EPI 1: QKV scatter (+bias).
#define BM 128
#define BN 128
#define BKk 64

template <int EPI>
__global__ __launch_bounds__(256) void k_gemm(
    const unsigned short* __restrict__ A, const unsigned short* __restrict__ Bt,
    const float* __restrict__ bias, float* __restrict__ out,
    unsigned short* __restrict__ Qb, unsigned short* __restrict__ Kb,
    unsigned short* __restrict__ Vtb, int M, int Nw, int K) {
  __shared__ char smem[BM * BKk * 2 + BN * BKk * 2];  // 32 KiB
  char* As = smem;
  char* Bs = smem + BM * BKk * 2;
  int t = threadIdx.x;
  int w = t >> 6, lane = t & 63;
  int m0 = blockIdx.x * BM;
  int n0 = blockIdx.y * BN;
  int wr = w >> 1, wc = w & 1;

  f32x4 acc[4][4] = {};

  for (int kt = 0; kt < K / BKk; ++kt) {
    __syncthreads();
    int k0 = kt * BKk;
#pragma unroll
    for (int it = 0; it < 4; ++it) {
      int o = it * 4096 + t * 16;
      int row = o >> 7, inb = o & 127;
      int sb = inb ^ ((row & 7) << 4);
      gl_lds16(&A[(size_t)(m0 + row) * K + k0 + (sb >> 1)], As + it * 4096 + w * 1024);
    }
#pragma unroll
    for (int it = 0; it < 4; ++it) {
      int o = it * 4096 + t * 16;
      int row = o >> 7, inb = o & 127;
      int sb = inb ^ ((row & 7) << 4);
      gl_lds16(&Bt[(size_t)(n0 + row) * K + k0 + (sb >> 1)], Bs + it * 4096 + w * 1024);
    }
    __syncthreads();
#pragma unroll
    for (int ks = 0; ks < 2; ++ks) {
      int kb = ks * 64 + ((lane >> 4) << 4);
      bf16x8 av[4], bv[4];
#pragma unroll
      for (int mi = 0; mi < 4; ++mi) {
        int row = wr * 64 + mi * 16 + (lane & 15);
        av[mi] = *(const bf16x8*)(As + row * 128 + (kb ^ ((row & 7) << 4)));
      }
#pragma unroll
      for (int ni = 0; ni < 4; ++ni) {
        int row = wc * 64 + ni * 16 + (lane & 15);
        bv[ni] = *(const bf16x8*)(Bs + row * 128 + (kb ^ ((row & 7) << 4)));
      }
#pragma unroll
      for (int mi = 0; mi < 4; ++mi)
#pragma unroll
        for (int ni = 0; ni < 4; ++ni)
          acc[mi][ni] = __builtin_amdgcn_mfma_f32_16x16x32_bf16(av[mi], bv[ni], acc[mi][ni], 0, 0, 0);
    }
  }

#pragma unroll
  for (int mi = 0; mi < 4; ++mi) {
#pragma unroll
    for (int ni = 0; ni < 4; ++ni) {
      int col = n0 + wc * 64 + ni * 16 + (lane & 15);
      float bvs = bias[col];
#pragma unroll
      for (int j = 0; j < 4; ++j) {
        int row = m0 + wr * 64 + mi * 16 + ((lane >> 4) << 2) + j;
        float val = acc[mi][ni][j] + bvs;
        if constexpr (EPI == 0) {
          out[(size_t)row * Nw + col] = val;
        } else {
          int bI = row >> 10, n = row & 1023;
          int typ = col / 768, within = col % 768;
          int h = within >> 6, d = within & 63;
          int bh = bI * 12 + h;
          unsigned short bf = f2bf(val);
          if (typ == 0)      Qb[((size_t)bh * 1024 + n) * 64 + d] = bf;
          else if (typ == 1) Kb[((size_t)bh * 1024 + n) * 64 + d] = bf;
          else               Vtb[((size_t)bh * 64 + d) * 1024 + n] = bf;
        }
      }
    }
  }
}

// ---------------- fused flash attention ------------------------------
// grid (16 nblk, 96 bh), 256 thr (4 waves). Wave w: 16 q-rows.
// K: [BH][N][64] bf16, Vt: [BH][64][N] bf16. Oa: [8192][768] bf16.
__global__ __launch_bounds__(256) void k_attn(
    const unsigned short* __restrict__ Q, const unsigned short* __restrict__ K,
    const unsigned short* __restrict__ Vt, unsigned short* __restrict__ Oa) {
  __shared__ char smem[8192 * 3];  // Ks, Vs, Ps
  char* Ks = smem;
  char* Vs = smem + 8192;
  char* Ps = smem + 16384;
  int t = threadIdx.x, w = t >> 6, lane = t & 63;
  int n0 = blockIdx.x * 64;
  int bh = blockIdx.y;
  int bI = bh / 12, h = bh % 12;

  // Q fragments (held in registers for the whole kernel)
  bf16x8 qf[2];
  {
    size_t qrow = ((size_t)bh * 1024 + n0 + w * 16 + (lane & 15)) * 128;  // bytes
    int kb = (lane >> 4) << 4;
    qf[0] = *(const bf16x8*)((const char*)Q + qrow + kb);
    qf[1] = *(const bf16x8*)((const char*)Q + qrow + 64 + kb);
  }

  f32x4 acc[4] = {};
  float mrun[4], lrun[4];
#pragma unroll
  for (int j = 0; j < 4; ++j) { mrun[j] = -INFINITY; lrun[j] = 0.f; }

  for (int mt = 0; mt < 16; ++mt) {
    int m0 = mt * 64;
    __syncthreads();
#pragma unroll
    for (int it = 0; it < 2; ++it) {
      int o = it * 4096 + t * 16;
      int row = o >> 7, inb = o & 127;
      int sb = inb ^ ((row & 7) << 4);
      gl_lds16((const char*)K + ((size_t)bh * 1024 + m0 + row) * 128 + sb,
               Ks + it * 4096 + w * 1024);
      gl_lds16((const char*)Vt + ((size_t)bh * 64 + row) * 2048 + m0 * 2 + sb,
               Vs + it * 4096 + w * 1024);
    }
    __syncthreads();

    // S = Q K^T  (wave's 16 rows x 64 cols)
    f32x4 s[4] = {};
#pragma unroll
    for (int ks = 0; ks < 2; ++ks) {
      int kb = ks * 64 + ((lane >> 4) << 4);
#pragma unroll
      for (int f = 0; f < 4; ++f) {
        int row = f * 16 + (lane & 15);
        bf16x8 kv = *(const bf16x8*)(Ks + row * 128 + (kb ^ ((row & 7) << 4)));
        s[f] = __builtin_amdgcn_mfma_f32_16x16x32_bf16(qf[ks], kv, s[f], 0, 0, 0);
      }
    }
#pragma unroll
    for (int f = 0; f < 4; ++f)
#pragma unroll
      for (int j = 0; j < 4; ++j) s[f][j] *= SCALE_F;

    // online softmax: row stats (rows live on (lane>>4)*4+j across 16-lane groups)
    float pmax[4], rsum[4], alpha[4];
#pragma unroll
    for (int j = 0; j < 4; ++j)
      pmax[j] = fmaxf(fmaxf(s[0][j], s[1][j]), fmaxf(s[2][j], s[3][j]));
#pragma unroll
    for (int off = 1; off < 16; off <<= 1)
#pragma unroll
      for (int j = 0; j < 4; ++j) pmax[j] = fmaxf(pmax[j], __shfl_xor(pmax[j], off, 64));
#pragma unroll
    for (int j = 0; j < 4; ++j) {
      float mnew = fmaxf(mrun[j], pmax[j]);
      alpha[j] = __expf(mrun[j] - mnew);
      mrun[j] = mnew;
    }
#pragma unroll
    for (int f = 0; f < 4; ++f)
#pragma unroll
      for (int j = 0; j < 4; ++j) s[f][j] = __expf(s[f][j] - mrun[j]);
#pragma unroll
    for (int j = 0; j < 4; ++j) rsum[j] = s[0][j] + s[1][j] + s[2][j] + s[3][j];
#pragma unroll
    for (int off = 1; off < 16; off <<= 1)
#pragma unroll
      for (int j = 0; j < 4; ++j) rsum[j] += __shfl_xor(rsum[j], off, 64);
#pragma unroll
    for (int j = 0; j < 4; ++j) lrun[j] = lrun[j] * alpha[j] + rsum[j];
#pragma unroll
    for (int fd = 0; fd < 4; ++fd)
#pragma unroll
      for (int j = 0; j < 4; ++j) acc[fd][j] *= alpha[j];

    // P -> per-wave LDS (swizzled), then A-fragments for PV
    char* Pw = Ps + w * 2048;
#pragma unroll
    for (int f = 0; f < 4; ++f) {
      int colb = (f * 16 + (lane & 15)) * 2;
#pragma unroll
      for (int j = 0; j < 4; ++j) {
        int prow = ((lane >> 4) << 2) + j;
        *(unsigned short*)(Pw + prow * 128 + (colb ^ ((prow & 7) << 4))) = f2bf(s[f][j]);
      }
    }
#pragma unroll
    for (int ks = 0; ks < 2; ++ks) {
      int kb = ks * 64 + ((lane >> 4) << 4);
      int arow = lane & 15;
      bf16x8 pa = *(const bf16x8*)(Pw + arow * 128 + (kb ^ ((arow & 7) << 4)));
#pragma unroll
      for (int fd = 0; fd < 4; ++fd) {
        int vrow = fd * 16 + (lane & 15);
        bf16x8 vv = *(const bf16x8*)(Vs + vrow * 128 + (kb ^ ((vrow & 7) << 4)));
        acc[fd] = __builtin_amdgcn_mfma_f32_16x16x32_bf16(pa, vv, acc[fd], 0, 0, 0);
      }
    }
  }

  // epilogue: out[b][n][h*64+d] bf16
#pragma unroll
  for (int j = 0; j < 4; ++j) {
    float inv = 1.0f / lrun[j];
    int n = n0 + w * 16 + ((lane >> 4) << 2) + j;
    size_t rowb = ((size_t)bI * 1024 + n) * 768 + h * 64;
#pragma unroll
    for (int fd = 0; fd < 4; ++fd)
      Oa[rowb + fd * 16 + (lane & 15)] = f2bf(acc[fd][j] * inv);
  }
}

// ---------------------------------------------------------------------
extern "C" void kernel_launch(void* const* d_in, const int* in_sizes, int n_in,
                              void* d_out, int out_size, void* d_ws, size_t ws_size,
                              hipStream_t stream) {
  const float* x = (const float*)d_in[0];
  const float* Wqkv = (const float*)d_in[1];
  const float* bqkv = (const float*)d_in[2];
  const float* Wproj = (const float*)d_in[3];
  const float* bproj = (const float*)d_in[4];
  float* out = (float*)d_out;

  char* ws = (char*)d_ws;
  unsigned short* xb  = (unsigned short*)(ws);                      // 12,582,912 B
  unsigned short* wqt = (unsigned short*)(ws + 12582912);           //  3,538,944 B
  unsigned short* wpt = (unsigned short*)(ws + 16121856);           //  1,179,648 B
  unsigned short* Qb  = (unsigned short*)(ws + 17301504);           // 12,582,912 B
  unsigned short* Kb  = (unsigned short*)(ws + 29884416);           // 12,582,912 B
  unsigned short* Vtb = (unsigned short*)(ws + 42467328);           // 12,582,912 B
  unsigned short* Oa  = (unsigned short*)(ws + 55050240);           // 12,582,912 B -> 67,633,152 total

  k_cvt_x<<<dim3(6144), dim3(256), 0, stream>>>(x, xb, (Bb * Nn_ * Cc_) / 4);
  k_transpose<768, 2304><<<dim3(36, 12), dim3(256), 0, stream>>>(Wqkv, wqt);
  k_transpose<768, 768><<<dim3(12, 12), dim3(256), 0, stream>>>(Wproj, wpt);
  k_gemm<1><<<dim3(64, 18), dim3(256), 0, stream>>>(xb, wqt, bqkv, nullptr, Qb, Kb, Vtb,
                                                    8192, 2304, 768);
  k_attn<<<dim3(16, 96), dim3(256), 0, stream>>>(Qb, Kb, Vtb, Oa);
  k_gemm<0><<<dim3(64, 6), dim3(256), 0, stream>>>(Oa, wpt, bproj, out, nullptr, nullptr, nullptr,
                                                   8192, 768, 768);
}

// Round 2
// 143.437 us; speedup vs baseline: 1.2912x; 1.2912x over previous
//
#include <hip/hip_runtime.h>
#include <hip/hip_bf16.h>
#include <stdint.h>

// Problem constants
#define Bb 8
#define Nn_ 1024
#define Cc_ 768
#define Hh 12
#define HDd 64
#define BHh 96
#define SCALE_F 0.03608439182435161f            // 768^-0.5
#define CL2F (0.03608439182435161f * 1.4426950408889634f)  // SCALE * log2(e)
#define THRRAW (3.0f / CL2F)                    // defer-max threshold (P <= 8)

typedef __attribute__((ext_vector_type(4))) float f32x4;
typedef __attribute__((ext_vector_type(8))) __bf16 bf16x8;

__device__ __forceinline__ unsigned short f2bf(float f) {
  uint32_t u = __builtin_bit_cast(uint32_t, f);
  uint32_t r = (u + 0x7fffu + ((u >> 16) & 1u)) >> 16;
  return (unsigned short)r;
}

__device__ __forceinline__ uint32_t cvtpk(float a, float b) {
  uint32_t r;
  asm("v_cvt_pk_bf16_f32 %0, %1, %2" : "=v"(r) : "v"(a), "v"(b));
  return r;
}

__device__ __forceinline__ f32x4 mfma16(bf16x8 a, bf16x8 b, f32x4 c) {
  return __builtin_amdgcn_mfma_f32_16x16x32_bf16(a, b, c, 0, 0, 0);
}

typedef const __attribute__((address_space(1))) uint32_t* gas1_t;
typedef __attribute__((address_space(3))) uint32_t* las3_t;
__device__ __forceinline__ void gl_lds16(const void* g, void* l) {
  __builtin_amdgcn_global_load_lds((gas1_t)g, (las3_t)l, 16, 0, 0);
}

// ---------------- cast x (f32 -> bf16), 4 elems/thread ----------------
__global__ void k_cvt_x(const float* __restrict__ x, unsigned short* __restrict__ xb, int n4) {
  int i = blockIdx.x * blockDim.x + threadIdx.x;
  if (i >= n4) return;
  float4 v = ((const float4*)x)[i];
  ushort4 o;
  o.x = f2bf(v.x); o.y = f2bf(v.y); o.z = f2bf(v.z); o.w = f2bf(v.w);
  ((ushort4*)xb)[i] = o;
}

// ------------- transpose f32 [R][CC] -> bf16 [CC][R] ------------------
template <int R, int CC>
__global__ void k_transpose(const float* __restrict__ src, unsigned short* __restrict__ dst) {
  __shared__ unsigned short tile[64][65];
  int c0 = blockIdx.x * 64;
  int r0 = blockIdx.y * 64;
  int t = threadIdx.x;
#pragma unroll
  for (int i = 0; i < 16; ++i) {
    int idx = t + 256 * i;
    int r = idx >> 6, c = idx & 63;
    tile[r][c] = f2bf(src[(size_t)(r0 + r) * CC + c0 + c]);
  }
  __syncthreads();
#pragma unroll
  for (int i = 0; i < 16; ++i) {
    int idx = t + 256 * i;
    int a = idx >> 6, bq = idx & 63;
    dst[(size_t)(c0 + a) * R + r0 + bq] = tile[bq][a];
  }
}

// ---------------- GEMM: A[M][K]bf16 x Bt[N][K]bf16 --------------------
#define BM 128
#define BN 128
#define BKk 64

template <int EPI>
__global__ __launch_bounds__(256) void k_gemm(
    const unsigned short* __restrict__ A, const unsigned short* __restrict__ Bt,
    const float* __restrict__ bias, float* __restrict__ out,
    unsigned short* __restrict__ Qb, unsigned short* __restrict__ Kb,
    unsigned short* __restrict__ Vtb, int M, int Nw, int K) {
  __shared__ char smem[BM * BKk * 2 + BN * BKk * 2];  // 32 KiB
  char* As = smem;
  char* Bs = smem + BM * BKk * 2;
  int t = threadIdx.x;
  int w = t >> 6, lane = t & 63;
  int m0 = blockIdx.x * BM;
  int n0 = blockIdx.y * BN;
  int wr = w >> 1, wc = w & 1;

  f32x4 acc[4][4] = {};

  for (int kt = 0; kt < K / BKk; ++kt) {
    __syncthreads();
    int k0 = kt * BKk;
#pragma unroll
    for (int it = 0; it < 4; ++it) {
      int o = it * 4096 + t * 16;
      int row = o >> 7, inb = o & 127;
      int sb = inb ^ ((row & 7) << 4);
      gl_lds16(&A[(size_t)(m0 + row) * K + k0 + (sb >> 1)], As + it * 4096 + w * 1024);
    }
#pragma unroll
    for (int it = 0; it < 4; ++it) {
      int o = it * 4096 + t * 16;
      int row = o >> 7, inb = o & 127;
      int sb = inb ^ ((row & 7) << 4);
      gl_lds16(&Bt[(size_t)(n0 + row) * K + k0 + (sb >> 1)], Bs + it * 4096 + w * 1024);
    }
    __syncthreads();
#pragma unroll
    for (int ks = 0; ks < 2; ++ks) {
      int kb = ks * 64 + ((lane >> 4) << 4);
      bf16x8 av[4], bv[4];
#pragma unroll
      for (int mi = 0; mi < 4; ++mi) {
        int row = wr * 64 + mi * 16 + (lane & 15);
        av[mi] = *(const bf16x8*)(As + row * 128 + (kb ^ ((row & 7) << 4)));
      }
#pragma unroll
      for (int ni = 0; ni < 4; ++ni) {
        int row = wc * 64 + ni * 16 + (lane & 15);
        bv[ni] = *(const bf16x8*)(Bs + row * 128 + (kb ^ ((row & 7) << 4)));
      }
#pragma unroll
      for (int mi = 0; mi < 4; ++mi)
#pragma unroll
        for (int ni = 0; ni < 4; ++ni)
          acc[mi][ni] = __builtin_amdgcn_mfma_f32_16x16x32_bf16(av[mi], bv[ni], acc[mi][ni], 0, 0, 0);
    }
  }

#pragma unroll
  for (int mi = 0; mi < 4; ++mi) {
#pragma unroll
    for (int ni = 0; ni < 4; ++ni) {
      int col = n0 + wc * 64 + ni * 16 + (lane & 15);
      float bvs = bias[col];
#pragma unroll
      for (int j = 0; j < 4; ++j) {
        int row = m0 + wr * 64 + mi * 16 + ((lane >> 4) << 2) + j;
        float val = acc[mi][ni][j] + bvs;
        if constexpr (EPI == 0) {
          out[(size_t)row * Nw + col] = val;
        } else {
          int bI = row >> 10, n = row & 1023;
          int typ = col / 768, within = col % 768;
          int h = within >> 6, d = within & 63;
          int bh = bI * 12 + h;
          unsigned short bf = f2bf(val);
          if (typ == 0)      Qb[((size_t)bh * 1024 + n) * 64 + d] = bf;
          else if (typ == 1) Kb[((size_t)bh * 1024 + n) * 64 + d] = bf;
          else               Vtb[((size_t)bh * 64 + d) * 1024 + n] = bf;
        }
      }
    }
  }
}

// ---------------- fused flash attention (swapped QK^T) ----------------
// grid (8 nblk, 96 bh), 256 thr (4 waves). Wave w: 32 q-rows.
// K: [BH][N][64] bf16, Vt: [BH][64][N] bf16. Oa: [8192][768] bf16.
// Double-buffered K/V staging (one barrier per KV tile).
__global__ __launch_bounds__(256, 3) void k_attn(
    const unsigned short* __restrict__ Q, const unsigned short* __restrict__ K,
    const unsigned short* __restrict__ Vt, unsigned short* __restrict__ Oa) {
  __shared__ char smem[49152];
  char* Ks = smem;           // 2 x 8192
  char* Vs = smem + 16384;   // 2 x 8192
  char* Ps = smem + 32768;   // 4 waves x 4096 ([32 q][64 kv] bf16, swizzled)
  int t = threadIdx.x, w = t >> 6, lane = t & 63;
  int g = lane >> 4, l15 = lane & 15;
  int n0 = blockIdx.x * 128;
  int bh = blockIdx.y;
  int bI = bh / 12, h = bh % 12;
  char* Pw = Ps + w * 4096;

  // Q as B-fragments: qf[qf_i][ks]; lane reads Q[q row][16B chunk]
  bf16x8 qf[2][2];
  {
    const char* qbase = (const char*)Q + ((size_t)bh * 1024 + n0 + w * 32 + l15) * 128 + g * 16;
    qf[0][0] = *(const bf16x8*)(qbase);
    qf[0][1] = *(const bf16x8*)(qbase + 64);
    qf[1][0] = *(const bf16x8*)(qbase + 16 * 128);
    qf[1][1] = *(const bf16x8*)(qbase + 16 * 128 + 64);
  }

  f32x4 acc[2][4] = {};  // [qf][fd]
  float mrun[2] = {-INFINITY, -INFINITY};
  float lrun[2] = {0.f, 0.f};

  // staging geometry (per-thread, loop-invariant)
  int o0 = t * 16, o1 = t * 16 + 4096;
  int r0 = o0 >> 7, r1 = o1 >> 7;
  int sb0 = (o0 & 127) ^ ((r0 & 7) << 4);
  int sb1 = (o1 & 127) ^ ((r1 & 7) << 4);
  const char* Kg = (const char*)K + ((size_t)bh * 1024) * 128;
  const char* Vg = (const char*)Vt + ((size_t)bh * 64) * 2048;

  // prologue: stage tile 0 into buffer 0
  gl_lds16(Kg + (size_t)r0 * 128 + sb0, Ks + w * 1024);
  gl_lds16(Kg + (size_t)r1 * 128 + sb1, Ks + 4096 + w * 1024);
  gl_lds16(Vg + (size_t)r0 * 2048 + sb0, Vs + w * 1024);
  gl_lds16(Vg + (size_t)r1 * 2048 + sb1, Vs + 4096 + w * 1024);
  __syncthreads();

  for (int mt = 0; mt < 16; ++mt) {
    int cur = mt & 1;
    char* Kc = Ks + cur * 8192;
    char* Vc = Vs + cur * 8192;
    if (mt < 15) {  // prefetch next tile into other buffer
      int m1 = (mt + 1) * 64;
      char* Kn = Ks + (cur ^ 1) * 8192;
      char* Vn = Vs + (cur ^ 1) * 8192;
      gl_lds16(Kg + (size_t)(m1 + r0) * 128 + sb0, Kn + w * 1024);
      gl_lds16(Kg + (size_t)(m1 + r1) * 128 + sb1, Kn + 4096 + w * 1024);
      gl_lds16(Vg + (size_t)r0 * 2048 + m1 * 2 + sb0, Vn + w * 1024);
      gl_lds16(Vg + (size_t)r1 * 2048 + m1 * 2 + sb1, Vn + 4096 + w * 1024);
    }

    // S^T = K Q^T : s[f][qf], lane holds S[q = qf*16 + l15][kv = f*16 + g*4 + j]
    f32x4 s[4][2] = {};
#pragma unroll
    for (int ks = 0; ks < 2; ++ks) {
#pragma unroll
      for (int f = 0; f < 4; ++f) {
        int row = f * 16 + l15;
        bf16x8 kv = *(const bf16x8*)(Kc + row * 128 + ((ks * 64 + g * 16) ^ ((row & 7) << 4)));
        s[f][0] = mfma16(kv, qf[0][ks], s[f][0]);
        s[f][1] = mfma16(kv, qf[1][ks], s[f][1]);
      }
    }

    // row max (lane-local over 16 regs, then 2 shuffles across g-groups)
    float pmax[2];
#pragma unroll
    for (int q = 0; q < 2; ++q) {
      float a0 = fmaxf(fmaxf(s[0][q][0], s[0][q][1]), fmaxf(s[0][q][2], s[0][q][3]));
      float a1 = fmaxf(fmaxf(s[1][q][0], s[1][q][1]), fmaxf(s[1][q][2], s[1][q][3]));
      float a2 = fmaxf(fmaxf(s[2][q][0], s[2][q][1]), fmaxf(s[2][q][2], s[2][q][3]));
      float a3 = fmaxf(fmaxf(s[3][q][0], s[3][q][1]), fmaxf(s[3][q][2], s[3][q][3]));
      float pm = fmaxf(fmaxf(a0, a1), fmaxf(a2, a3));
      pm = fmaxf(pm, __shfl_xor(pm, 16, 64));
      pm = fmaxf(pm, __shfl_xor(pm, 32, 64));
      pmax[q] = pm;
    }

    // defer-max: only rescale when max grew past threshold (wave-uniform)
    bool upd = (pmax[0] > mrun[0] + THRRAW) || (pmax[1] > mrun[1] + THRRAW);
    if (__any(upd)) {
#pragma unroll
      for (int q = 0; q < 2; ++q) {
        float mnew = fmaxf(mrun[q], pmax[q]);
        float alpha = __builtin_amdgcn_exp2f((mrun[q] - mnew) * CL2F);
        mrun[q] = mnew;
        lrun[q] *= alpha;
#pragma unroll
        for (int j = 0; j < 4; ++j) {
          float aj = __shfl(alpha, g * 4 + j, 64);
          acc[q][0][j] *= aj; acc[q][1][j] *= aj;
          acc[q][2][j] *= aj; acc[q][3][j] *= aj;
        }
      }
    }

    // P = exp2((s - m) * c), row-sum, pack to bf16, store to per-wave LDS
#pragma unroll
    for (int q = 0; q < 2; ++q) {
      float nm = -mrun[q] * CL2F;
      int prow = q * 16 + l15;
      int pbase = prow * 128;
      int swz = (prow & 7) << 4;
      float rs = 0.f;
#pragma unroll
      for (int f = 0; f < 4; ++f) {
        float p0 = __builtin_amdgcn_exp2f(fmaf(s[f][q][0], CL2F, nm));
        float p1 = __builtin_amdgcn_exp2f(fmaf(s[f][q][1], CL2F, nm));
        float p2 = __builtin_amdgcn_exp2f(fmaf(s[f][q][2], CL2F, nm));
        float p3 = __builtin_amdgcn_exp2f(fmaf(s[f][q][3], CL2F, nm));
        rs += (p0 + p1) + (p2 + p3);
        uint2 pk;
        pk.x = cvtpk(p0, p1);
        pk.y = cvtpk(p2, p3);
        *(uint2*)(Pw + pbase + ((f * 32 + g * 8) ^ swz)) = pk;
      }
      rs += __shfl_xor(rs, 16, 64);
      rs += __shfl_xor(rs, 32, 64);
      lrun[q] += rs;
    }

    // O += P V : A-frag = P rows, B-frag = V^T rows
#pragma unroll
    for (int ks = 0; ks < 2; ++ks) {
      bf16x8 pa[2];
#pragma unroll
      for (int q = 0; q < 2; ++q) {
        int prow = q * 16 + l15;
        pa[q] = *(const bf16x8*)(Pw + prow * 128 + ((ks * 64 + g * 16) ^ ((prow & 7) << 4)));
      }
#pragma unroll
      for (int fd = 0; fd < 4; ++fd) {
        int vrow = fd * 16 + l15;
        bf16x8 vv = *(const bf16x8*)(Vc + vrow * 128 + ((ks * 64 + g * 16) ^ ((vrow & 7) << 4)));
        acc[0][fd] = mfma16(pa[0], vv, acc[0][fd]);
        acc[1][fd] = mfma16(pa[1], vv, acc[1][fd]);
      }
    }
    __syncthreads();  // drains this iteration's prefetch (vmcnt 0) + protects buffers
  }

  // epilogue: out[b][n][h*64+d] bf16, rows q = qf*16 + g*4 + j
#pragma unroll
  for (int q = 0; q < 2; ++q) {
#pragma unroll
    for (int j = 0; j < 4; ++j) {
      float lv = __shfl(lrun[q], g * 4 + j, 64);
      float inv = 1.0f / lv;
      int n = n0 + w * 32 + q * 16 + g * 4 + j;
      size_t rowb = ((size_t)bI * 1024 + n) * 768 + h * 64;
#pragma unroll
      for (int fd = 0; fd < 4; ++fd)
        Oa[rowb + fd * 16 + l15] = (unsigned short)(cvtpk(acc[q][fd][j] * inv, 0.f) & 0xffffu);
    }
  }
}

// ---------------------------------------------------------------------
extern "C" void kernel_launch(void* const* d_in, const int* in_sizes, int n_in,
                              void* d_out, int out_size, void* d_ws, size_t ws_size,
                              hipStream_t stream) {
  const float* x = (const float*)d_in[0];
  const float* Wqkv = (const float*)d_in[1];
  const float* bqkv = (const float*)d_in[2];
  const float* Wproj = (const float*)d_in[3];
  const float* bproj = (const float*)d_in[4];
  float* out = (float*)d_out;

  char* ws = (char*)d_ws;
  unsigned short* xb  = (unsigned short*)(ws);                      // 12,582,912 B
  unsigned short* wqt = (unsigned short*)(ws + 12582912);           //  3,538,944 B
  unsigned short* wpt = (unsigned short*)(ws + 16121856);           //  1,179,648 B
  unsigned short* Qb  = (unsigned short*)(ws + 17301504);           // 12,582,912 B
  unsigned short* Kb  = (unsigned short*)(ws + 29884416);           // 12,582,912 B
  unsigned short* Vtb = (unsigned short*)(ws + 42467328);           // 12,582,912 B
  unsigned short* Oa  = (unsigned short*)(ws + 55050240);           // 12,582,912 B

  k_cvt_x<<<dim3(6144), dim3(256), 0, stream>>>(x, xb, (Bb * Nn_ * Cc_) / 4);
  k_transpose<768, 2304><<<dim3(36, 12), dim3(256), 0, stream>>>(Wqkv, wqt);
  k_transpose<768, 768><<<dim3(12, 12), dim3(256), 0, stream>>>(Wproj, wpt);
  k_gemm<1><<<dim3(64, 18), dim3(256), 0, stream>>>(xb, wqt, bqkv, nullptr, Qb, Kb, Vtb,
                                                    8192, 2304, 768);
  k_attn<<<dim3(8, 96), dim3(256), 0, stream>>>(Qb, Kb, Vtb, Oa);
  k_gemm<0><<<dim3(64, 6), dim3(256), 0, stream>>>(Oa, wpt, bproj, out, nullptr, nullptr, nullptr,
                                                   8192, 768, 768);
}

// Round 3
// 119.166 us; speedup vs baseline: 1.5542x; 1.2037x over previous
//
#include <hip/hip_runtime.h>
#include <hip/hip_bf16.h>
#include <stdint.h>

// Problem constants
#define Bb 8
#define Nn_ 1024
#define Cc_ 768
#define Hh 12
#define HDd 64
#define BHh 96
#define SCALE_F 0.03608439182435161f            // 768^-0.5
#define CL2F (0.03608439182435161f * 1.4426950408889634f)  // SCALE * log2(e)
#define THRRAW (3.0f / CL2F)                    // defer-max threshold (P <= 8)

typedef __attribute__((ext_vector_type(4))) float f32x4;
typedef __attribute__((ext_vector_type(8))) __bf16 bf16x8;

__device__ __forceinline__ unsigned short f2bf(float f) {
  uint32_t u = __builtin_bit_cast(uint32_t, f);
  uint32_t r = (u + 0x7fffu + ((u >> 16) & 1u)) >> 16;
  return (unsigned short)r;
}

__device__ __forceinline__ uint32_t cvtpk(float a, float b) {
  uint32_t r;
  asm("v_cvt_pk_bf16_f32 %0, %1, %2" : "=v"(r) : "v"(a), "v"(b));
  return r;
}

__device__ __forceinline__ f32x4 mfma16(bf16x8 a, bf16x8 b, f32x4 c) {
  return __builtin_amdgcn_mfma_f32_16x16x32_bf16(a, b, c, 0, 0, 0);
}

typedef const __attribute__((address_space(1))) uint32_t* gas1_t;
typedef __attribute__((address_space(3))) uint32_t* las3_t;
__device__ __forceinline__ void gl_lds16(const void* g, void* l) {
  __builtin_amdgcn_global_load_lds((gas1_t)g, (las3_t)l, 16, 0, 0);
}

// ---------------- cast x (f32 -> bf16), 4 elems/thread ----------------
__global__ void k_cvt_x(const float* __restrict__ x, unsigned short* __restrict__ xb, int n4) {
  int i = blockIdx.x * blockDim.x + threadIdx.x;
  if (i >= n4) return;
  float4 v = ((const float4*)x)[i];
  ushort4 o;
  o.x = f2bf(v.x); o.y = f2bf(v.y); o.z = f2bf(v.z); o.w = f2bf(v.w);
  ((ushort4*)xb)[i] = o;
}

// ------------- transpose f32 [R][CC] -> bf16 [CC][R] ------------------
template <int R, int CC>
__global__ void k_transpose(const float* __restrict__ src, unsigned short* __restrict__ dst) {
  __shared__ unsigned short tile[64][65];
  int c0 = blockIdx.x * 64;
  int r0 = blockIdx.y * 64;
  int t = threadIdx.x;
#pragma unroll
  for (int i = 0; i < 16; ++i) {
    int idx = t + 256 * i;
    int r = idx >> 6, c = idx & 63;
    tile[r][c] = f2bf(src[(size_t)(r0 + r) * CC + c0 + c]);
  }
  __syncthreads();
#pragma unroll
  for (int i = 0; i < 16; ++i) {
    int idx = t + 256 * i;
    int a = idx >> 6, bq = idx & 63;
    dst[(size_t)(c0 + a) * R + r0 + bq] = tile[bq][a];
  }
}

// ---------- transpose V bf16 [bh][1024][64] -> Vt [bh][64][1024] ------
__global__ __launch_bounds__(256) void k_transpose_v(const unsigned short* __restrict__ V,
                                                     unsigned short* __restrict__ Vt) {
  __shared__ unsigned short tile[64][72];
  int bh = blockIdx.y;
  int n0 = blockIdx.x * 64;
  int t = threadIdx.x;
  const unsigned short* src = V + ((size_t)bh * 1024 + n0) * 64;
#pragma unroll
  for (int i = 0; i < 4; ++i) {
    int idx = t + i * 256;       // 1024 ushort4 chunks
    int r = idx >> 4, c4 = idx & 15;
    ushort4 v = ((const ushort4*)src)[idx];
    tile[r][c4 * 4 + 0] = v.x; tile[r][c4 * 4 + 1] = v.y;
    tile[r][c4 * 4 + 2] = v.z; tile[r][c4 * 4 + 3] = v.w;
  }
  __syncthreads();
  unsigned short* dst = Vt + (size_t)bh * 64 * 1024 + n0;
#pragma unroll
  for (int i = 0; i < 4; ++i) {
    int idx = t + i * 256;
    int c = idx >> 4, n4 = idx & 15;
    ushort4 o;
    o.x = tile[n4 * 4 + 0][c]; o.y = tile[n4 * 4 + 1][c];
    o.z = tile[n4 * 4 + 2][c]; o.w = tile[n4 * 4 + 3][c];
    ((ushort4*)(dst + (size_t)c * 1024))[n4] = o;
  }
}

// ---------------- GEMM: A[M][K]bf16 x Bt[N][K]bf16 --------------------
// 128x128 tile, BK=64, 4 waves (2x2). 2-phase pipeline: double-buffered
// LDS, STAGE(next) issued before ds_read+MFMA(cur), ONE barrier per K-tile.
// EPI 0: out fp32 [M][N] (+bias).  EPI 1: QKV row-layout scatter (+bias).
#define BM 128
#define BN 128

template <int EPI>
__global__ __launch_bounds__(256, 2) void k_gemm(
    const unsigned short* __restrict__ A, const unsigned short* __restrict__ Bt,
    const float* __restrict__ bias, float* __restrict__ out,
    unsigned short* __restrict__ Qb, unsigned short* __restrict__ Kb,
    unsigned short* __restrict__ Vb, int M, int Nw, int K) {
  __shared__ char smem[2][32768];  // per buffer: As 16KB + Bs 16KB
  int t = threadIdx.x;
  int w = t >> 6, lane = t & 63;
  int g = lane >> 4, l15 = lane & 15;
  int m0 = blockIdx.x * BM;
  int n0 = blockIdx.y * BN;
  int wr = w >> 1, wc = w & 1;

  f32x4 acc[4][4] = {};

  // per-thread staging geometry (loop-invariant)
  int soff[4], srow[4], ssb[4];
#pragma unroll
  for (int it = 0; it < 4; ++it) {
    int off = it * 4096 + t * 16;
    soff[it] = it * 4096 + w * 1024;     // LDS dest base (wave-uniform + lane*16)
    srow[it] = off >> 7;
    ssb[it] = (off & 127) ^ ((srow[it] & 7) << 4);
  }

  auto STAGE = [&](int buf, int kt) {
    int k0 = kt * 64;
    char* As = smem[buf];
    char* Bs = smem[buf] + 16384;
#pragma unroll
    for (int it = 0; it < 4; ++it)
      gl_lds16(&A[(size_t)(m0 + srow[it]) * K + k0 + (ssb[it] >> 1)], As + soff[it]);
#pragma unroll
    for (int it = 0; it < 4; ++it)
      gl_lds16(&Bt[(size_t)(n0 + srow[it]) * K + k0 + (ssb[it] >> 1)], Bs + soff[it]);
  };

  STAGE(0, 0);
  __syncthreads();  // drains vmcnt(0)

  int nkt = K >> 6;
  for (int kt = 0; kt < nkt; ++kt) {
    int cur = kt & 1;
    if (kt + 1 < nkt) STAGE(cur ^ 1, kt + 1);  // prefetch flies under ds_read+MFMA
    char* As = smem[cur];
    char* Bs = smem[cur] + 16384;
    bf16x8 av[2][4], bv[2][4];
#pragma unroll
    for (int ks = 0; ks < 2; ++ks) {
      int kb = ks * 64 + g * 16;
#pragma unroll
      for (int mi = 0; mi < 4; ++mi) {
        int row = wr * 64 + mi * 16 + l15;
        av[ks][mi] = *(const bf16x8*)(As + row * 128 + (kb ^ ((row & 7) << 4)));
      }
#pragma unroll
      for (int ni = 0; ni < 4; ++ni) {
        int row = wc * 64 + ni * 16 + l15;
        bv[ks][ni] = *(const bf16x8*)(Bs + row * 128 + (kb ^ ((row & 7) << 4)));
      }
    }
#pragma unroll
    for (int ks = 0; ks < 2; ++ks)
#pragma unroll
      for (int mi = 0; mi < 4; ++mi)
#pragma unroll
        for (int ni = 0; ni < 4; ++ni)
          acc[mi][ni] = mfma16(av[ks][mi], bv[ks][ni], acc[mi][ni]);
    __syncthreads();  // drains prefetch (vmcnt 0) + protects both buffers
  }

#pragma unroll
  for (int mi = 0; mi < 4; ++mi) {
#pragma unroll
    for (int ni = 0; ni < 4; ++ni) {
      int col = n0 + wc * 64 + ni * 16 + l15;
      float bvs = bias[col];
#pragma unroll
      for (int j = 0; j < 4; ++j) {
        int row = m0 + wr * 64 + mi * 16 + g * 4 + j;
        float val = acc[mi][ni][j] + bvs;
        if constexpr (EPI == 0) {
          out[(size_t)row * Nw + col] = val;
        } else {
          int bI = row >> 10, n = row & 1023;
          int typ = col / 768, within = col % 768;
          int h = within >> 6, d = within & 63;
          int bh = bI * 12 + h;
          unsigned short bf = f2bf(val);
          unsigned short* dst = (typ == 0) ? Qb : (typ == 1) ? Kb : Vb;
          dst[((size_t)bh * 1024 + n) * 64 + d] = bf;
        }
      }
    }
  }
}

// ---------------- fused flash attention (swapped QK^T) ----------------
// grid (8 nblk, 96 bh), 256 thr (4 waves). Wave w: 32 q-rows.
// K: [BH][N][64] bf16, Vt: [BH][64][N] bf16. Oa: [8192][768] bf16.
__global__ __launch_bounds__(256, 3) void k_attn(
    const unsigned short* __restrict__ Q, const unsigned short* __restrict__ K,
    const unsigned short* __restrict__ Vt, unsigned short* __restrict__ Oa) {
  __shared__ char smem[49152];
  char* Ks = smem;           // 2 x 8192
  char* Vs = smem + 16384;   // 2 x 8192
  char* Ps = smem + 32768;   // 4 waves x 4096
  int t = threadIdx.x, w = t >> 6, lane = t & 63;
  int g = lane >> 4, l15 = lane & 15;
  int n0 = blockIdx.x * 128;
  int bh = blockIdx.y;
  int bI = bh / 12, h = bh % 12;
  char* Pw = Ps + w * 4096;

  bf16x8 qf[2][2];
  {
    const char* qbase = (const char*)Q + ((size_t)bh * 1024 + n0 + w * 32 + l15) * 128 + g * 16;
    qf[0][0] = *(const bf16x8*)(qbase);
    qf[0][1] = *(const bf16x8*)(qbase + 64);
    qf[1][0] = *(const bf16x8*)(qbase + 16 * 128);
    qf[1][1] = *(const bf16x8*)(qbase + 16 * 128 + 64);
  }

  f32x4 acc[2][4] = {};
  float mrun[2] = {-INFINITY, -INFINITY};
  float lrun[2] = {0.f, 0.f};

  int o0 = t * 16, o1 = t * 16 + 4096;
  int r0 = o0 >> 7, r1 = o1 >> 7;
  int sb0 = (o0 & 127) ^ ((r0 & 7) << 4);
  int sb1 = (o1 & 127) ^ ((r1 & 7) << 4);
  const char* Kg = (const char*)K + ((size_t)bh * 1024) * 128;
  const char* Vg = (const char*)Vt + ((size_t)bh * 64) * 2048;

  gl_lds16(Kg + (size_t)r0 * 128 + sb0, Ks + w * 1024);
  gl_lds16(Kg + (size_t)r1 * 128 + sb1, Ks + 4096 + w * 1024);
  gl_lds16(Vg + (size_t)r0 * 2048 + sb0, Vs + w * 1024);
  gl_lds16(Vg + (size_t)r1 * 2048 + sb1, Vs + 4096 + w * 1024);
  __syncthreads();

  for (int mt = 0; mt < 16; ++mt) {
    int cur = mt & 1;
    char* Kc = Ks + cur * 8192;
    char* Vc = Vs + cur * 8192;
    if (mt < 15) {
      int m1 = (mt + 1) * 64;
      char* Kn = Ks + (cur ^ 1) * 8192;
      char* Vn = Vs + (cur ^ 1) * 8192;
      gl_lds16(Kg + (size_t)(m1 + r0) * 128 + sb0, Kn + w * 1024);
      gl_lds16(Kg + (size_t)(m1 + r1) * 128 + sb1, Kn + 4096 + w * 1024);
      gl_lds16(Vg + (size_t)r0 * 2048 + m1 * 2 + sb0, Vn + w * 1024);
      gl_lds16(Vg + (size_t)r1 * 2048 + m1 * 2 + sb1, Vn + 4096 + w * 1024);
    }

    f32x4 s[4][2] = {};
#pragma unroll
    for (int ks = 0; ks < 2; ++ks) {
#pragma unroll
      for (int f = 0; f < 4; ++f) {
        int row = f * 16 + l15;
        bf16x8 kv = *(const bf16x8*)(Kc + row * 128 + ((ks * 64 + g * 16) ^ ((row & 7) << 4)));
        s[f][0] = mfma16(kv, qf[0][ks], s[f][0]);
        s[f][1] = mfma16(kv, qf[1][ks], s[f][1]);
      }
    }

    float pmax[2];
#pragma unroll
    for (int q = 0; q < 2; ++q) {
      float a0 = fmaxf(fmaxf(s[0][q][0], s[0][q][1]), fmaxf(s[0][q][2], s[0][q][3]));
      float a1 = fmaxf(fmaxf(s[1][q][0], s[1][q][1]), fmaxf(s[1][q][2], s[1][q][3]));
      float a2 = fmaxf(fmaxf(s[2][q][0], s[2][q][1]), fmaxf(s[2][q][2], s[2][q][3]));
      float a3 = fmaxf(fmaxf(s[3][q][0], s[3][q][1]), fmaxf(s[3][q][2], s[3][q][3]));
      float pm = fmaxf(fmaxf(a0, a1), fmaxf(a2, a3));
      pm = fmaxf(pm, __shfl_xor(pm, 16, 64));
      pm = fmaxf(pm, __shfl_xor(pm, 32, 64));
      pmax[q] = pm;
    }

    bool upd = (pmax[0] > mrun[0] + THRRAW) || (pmax[1] > mrun[1] + THRRAW);
    if (__any(upd)) {
#pragma unroll
      for (int q = 0; q < 2; ++q) {
        float mnew = fmaxf(mrun[q], pmax[q]);
        float alpha = __builtin_amdgcn_exp2f((mrun[q] - mnew) * CL2F);
        mrun[q] = mnew;
        lrun[q] *= alpha;
#pragma unroll
        for (int j = 0; j < 4; ++j) {
          float aj = __shfl(alpha, g * 4 + j, 64);
          acc[q][0][j] *= aj; acc[q][1][j] *= aj;
          acc[q][2][j] *= aj; acc[q][3][j] *= aj;
        }
      }
    }

#pragma unroll
    for (int q = 0; q < 2; ++q) {
      float nm = -mrun[q] * CL2F;
      int prow = q * 16 + l15;
      int pbase = prow * 128;
      int swz = (prow & 7) << 4;
      float rs = 0.f;
#pragma unroll
      for (int f = 0; f < 4; ++f) {
        float p0 = __builtin_amdgcn_exp2f(fmaf(s[f][q][0], CL2F, nm));
        float p1 = __builtin_amdgcn_exp2f(fmaf(s[f][q][1], CL2F, nm));
        float p2 = __builtin_amdgcn_exp2f(fmaf(s[f][q][2], CL2F, nm));
        float p3 = __builtin_amdgcn_exp2f(fmaf(s[f][q][3], CL2F, nm));
        rs += (p0 + p1) + (p2 + p3);
        uint2 pk;
        pk.x = cvtpk(p0, p1);
        pk.y = cvtpk(p2, p3);
        *(uint2*)(Pw + pbase + ((f * 32 + g * 8) ^ swz)) = pk;
      }
      rs += __shfl_xor(rs, 16, 64);
      rs += __shfl_xor(rs, 32, 64);
      lrun[q] += rs;
    }

#pragma unroll
    for (int ks = 0; ks < 2; ++ks) {
      bf16x8 pa[2];
#pragma unroll
      for (int q = 0; q < 2; ++q) {
        int prow = q * 16 + l15;
        pa[q] = *(const bf16x8*)(Pw + prow * 128 + ((ks * 64 + g * 16) ^ ((prow & 7) << 4)));
      }
#pragma unroll
      for (int fd = 0; fd < 4; ++fd) {
        int vrow = fd * 16 + l15;
        bf16x8 vv = *(const bf16x8*)(Vc + vrow * 128 + ((ks * 64 + g * 16) ^ ((vrow & 7) << 4)));
        acc[0][fd] = mfma16(pa[0], vv, acc[0][fd]);
        acc[1][fd] = mfma16(pa[1], vv, acc[1][fd]);
      }
    }
    __syncthreads();
  }

#pragma unroll
  for (int q = 0; q < 2; ++q) {
#pragma unroll
    for (int j = 0; j < 4; ++j) {
      float lv = __shfl(lrun[q], g * 4 + j, 64);
      float inv = 1.0f / lv;
      int n = n0 + w * 32 + q * 16 + g * 4 + j;
      size_t rowb = ((size_t)bI * 1024 + n) * 768 + h * 64;
#pragma unroll
      for (int fd = 0; fd < 4; ++fd)
        Oa[rowb + fd * 16 + l15] = (unsigned short)(cvtpk(acc[q][fd][j] * inv, 0.f) & 0xffffu);
    }
  }
}

// ---------------------------------------------------------------------
extern "C" void kernel_launch(void* const* d_in, const int* in_sizes, int n_in,
                              void* d_out, int out_size, void* d_ws, size_t ws_size,
                              hipStream_t stream) {
  const float* x = (const float*)d_in[0];
  const float* Wqkv = (const float*)d_in[1];
  const float* bqkv = (const float*)d_in[2];
  const float* Wproj = (const float*)d_in[3];
  const float* bproj = (const float*)d_in[4];
  float* out = (float*)d_out;

  char* ws = (char*)d_ws;
  unsigned short* xb  = (unsigned short*)(ws);                      // 12,582,912 B
  unsigned short* wqt = (unsigned short*)(ws + 12582912);           //  3,538,944 B
  unsigned short* wpt = (unsigned short*)(ws + 16121856);           //  1,179,648 B
  unsigned short* Qb  = (unsigned short*)(ws + 17301504);           // 12,582,912 B
  unsigned short* Kb  = (unsigned short*)(ws + 29884416);           // 12,582,912 B
  unsigned short* Vtb = (unsigned short*)(ws + 42467328);           // 12,582,912 B
  unsigned short* Oa  = (unsigned short*)(ws + 55050240);           // 12,582,912 B
  unsigned short* Vb  = Oa;  // V row-layout aliases Oa slot (dead before attn writes Oa)

  k_cvt_x<<<dim3(6144), dim3(256), 0, stream>>>(x, xb, (Bb * Nn_ * Cc_) / 4);
  k_transpose<768, 2304><<<dim3(36, 12), dim3(256), 0, stream>>>(Wqkv, wqt);
  k_transpose<768, 768><<<dim3(12, 12), dim3(256), 0, stream>>>(Wproj, wpt);
  k_gemm<1><<<dim3(64, 18), dim3(256), 0, stream>>>(xb, wqt, bqkv, nullptr, Qb, Kb, Vb,
                                                    8192, 2304, 768);
  k_transpose_v<<<dim3(16, 96), dim3(256), 0, stream>>>(Vb, Vtb);
  k_attn<<<dim3(8, 96), dim3(256), 0, stream>>>(Qb, Kb, Vtb, Oa);
  k_gemm<0><<<dim3(64, 6), dim3(256), 0, stream>>>(Oa, wpt, bproj, out, nullptr, nullptr, nullptr,
                                                   8192, 768, 768);
}

// Round 4
// 114.066 us; speedup vs baseline: 1.6237x; 1.0447x over previous
//
#include <hip/hip_runtime.h>
#include <hip/hip_bf16.h>
#include <stdint.h>

// Problem constants
#define Bb 8
#define Nn_ 1024
#define Cc_ 768
#define Hh 12
#define HDd 64
#define BHh 96
#define SCALE_F 0.03608439182435161f            // 768^-0.5
#define CL2F (0.03608439182435161f * 1.4426950408889634f)  // SCALE * log2(e)
#define THRRAW (3.0f / CL2F)                    // defer-max threshold (P <= 8)

typedef __attribute__((ext_vector_type(4))) float f32x4;
typedef __attribute__((ext_vector_type(8))) __bf16 bf16x8;

__device__ __forceinline__ unsigned short f2bf(float f) {
  uint32_t u = __builtin_bit_cast(uint32_t, f);
  uint32_t r = (u + 0x7fffu + ((u >> 16) & 1u)) >> 16;
  return (unsigned short)r;
}

__device__ __forceinline__ uint32_t cvtpk(float a, float b) {
  uint32_t r;
  asm("v_cvt_pk_bf16_f32 %0, %1, %2" : "=v"(r) : "v"(a), "v"(b));
  return r;
}

__device__ __forceinline__ f32x4 mfma16(bf16x8 a, bf16x8 b, f32x4 c) {
  return __builtin_amdgcn_mfma_f32_16x16x32_bf16(a, b, c, 0, 0, 0);
}

typedef const __attribute__((address_space(1))) uint32_t* gas1_t;
typedef __attribute__((address_space(3))) uint32_t* las3_t;
__device__ __forceinline__ void gl_lds16(const void* g, void* l) {
  __builtin_amdgcn_global_load_lds((gas1_t)g, (las3_t)l, 16, 0, 0);
}

#define VMCNT(n) asm volatile("s_waitcnt vmcnt(" #n ")" ::: "memory")
#define SBAR() __builtin_amdgcn_s_barrier()
#define SCHED_FENCE() __builtin_amdgcn_sched_barrier(0)

// ---------------- cast x (f32 -> bf16), 4 elems/thread ----------------
__global__ void k_cvt_x(const float* __restrict__ x, unsigned short* __restrict__ xb, int n4) {
  int i = blockIdx.x * blockDim.x + threadIdx.x;
  if (i >= n4) return;
  float4 v = ((const float4*)x)[i];
  ushort4 o;
  o.x = f2bf(v.x); o.y = f2bf(v.y); o.z = f2bf(v.z); o.w = f2bf(v.w);
  ((ushort4*)xb)[i] = o;
}

// ------------- transpose f32 [R][CC] -> bf16 [CC][R] ------------------
template <int R, int CC>
__global__ void k_transpose(const float* __restrict__ src, unsigned short* __restrict__ dst) {
  __shared__ unsigned short tile[64][65];
  int c0 = blockIdx.x * 64;
  int r0 = blockIdx.y * 64;
  int t = threadIdx.x;
#pragma unroll
  for (int i = 0; i < 16; ++i) {
    int idx = t + 256 * i;
    int r = idx >> 6, c = idx & 63;
    tile[r][c] = f2bf(src[(size_t)(r0 + r) * CC + c0 + c]);
  }
  __syncthreads();
#pragma unroll
  for (int i = 0; i < 16; ++i) {
    int idx = t + 256 * i;
    int a = idx >> 6, bq = idx & 63;
    dst[(size_t)(c0 + a) * R + r0 + bq] = tile[bq][a];
  }
}

// ---------- transpose V bf16 [bh][1024][64] -> Vt [bh][64][1024] ------
__global__ __launch_bounds__(256) void k_transpose_v(const unsigned short* __restrict__ V,
                                                     unsigned short* __restrict__ Vt) {
  __shared__ unsigned short tile[64][72];
  int bh = blockIdx.y;
  int n0 = blockIdx.x * 64;
  int t = threadIdx.x;
  const unsigned short* src = V + ((size_t)bh * 1024 + n0) * 64;
#pragma unroll
  for (int i = 0; i < 4; ++i) {
    int idx = t + i * 256;
    int r = idx >> 4, c4 = idx & 15;
    ushort4 v = ((const ushort4*)src)[idx];
    tile[r][c4 * 4 + 0] = v.x; tile[r][c4 * 4 + 1] = v.y;
    tile[r][c4 * 4 + 2] = v.z; tile[r][c4 * 4 + 3] = v.w;
  }
  __syncthreads();
  unsigned short* dst = Vt + (size_t)bh * 64 * 1024 + n0;
#pragma unroll
  for (int i = 0; i < 4; ++i) {
    int idx = t + i * 256;
    int c = idx >> 4, n4 = idx & 15;
    ushort4 o;
    o.x = tile[n4 * 4 + 0][c]; o.y = tile[n4 * 4 + 1][c];
    o.z = tile[n4 * 4 + 2][c]; o.w = tile[n4 * 4 + 3][c];
    ((ushort4*)(dst + (size_t)c * 1024))[n4] = o;
  }
}

// ---------------- GEMM: A[M][768]bf16 x Bt[N][768]bf16 ----------------
// 128x128 tile, BK=64 (12 K-steps, fully unrolled), 4 waves (2x2).
// Counted-vmcnt double buffer: STAGE(next); vmcnt(8); s_barrier; compute;
// s_barrier. LDS read pointers hoisted; buffers via +32768 immediates.
#define BM 128
#define BN 128

template <int EPI>
__global__ __launch_bounds__(256, 2) void k_gemm(
    const unsigned short* __restrict__ A, const unsigned short* __restrict__ Bt,
    const float* __restrict__ bias, float* __restrict__ out,
    unsigned short* __restrict__ Qb, unsigned short* __restrict__ Kb,
    unsigned short* __restrict__ Vb, int M, int Nw) {
  __shared__ char smem[2][32768];  // per buffer: As 16KB + Bs 16KB
  int t = threadIdx.x;
  int w = t >> 6, lane = t & 63;
  int g = lane >> 4, l15 = lane & 15;
  int m0 = blockIdx.x * BM;
  int n0 = blockIdx.y * BN;
  int wr = w >> 1, wc = w & 1;

  f32x4 acc[4][4] = {};

  // staging geometry (loop-invariant): 4 x 16B per thread per operand
  int soff[4];
  const char* gA[4];
  const char* gB[4];
#pragma unroll
  for (int it = 0; it < 4; ++it) {
    int off = it * 4096 + t * 16;
    soff[it] = it * 4096 + w * 1024;
    int row = off >> 7;
    int sb = (off & 127) ^ ((row & 7) << 4);
    gA[it] = (const char*)A + (size_t)(m0 + row) * 1536 + sb;
    gB[it] = (const char*)Bt + (size_t)(n0 + row) * 1536 + sb;
  }

  auto STG = [&](int buf, int kt) {
    char* As = smem[buf];
    char* Bs = smem[buf] + 16384;
#pragma unroll
    for (int it = 0; it < 4; ++it) gl_lds16(gA[it] + kt * 128, As + soff[it]);
#pragma unroll
    for (int it = 0; it < 4; ++it) gl_lds16(gB[it] + kt * 128, Bs + soff[it]);
  };

  // hoisted LDS read pointers (buffer 0); buffer 1 = +32768 immediate
  const char *pa[2][4], *pb[2][4];
#pragma unroll
  for (int ks = 0; ks < 2; ++ks) {
    int kb = ks * 64 + g * 16;
#pragma unroll
    for (int mi = 0; mi < 4; ++mi) {
      int rowA = wr * 64 + mi * 16 + l15;
      pa[ks][mi] = smem[0] + rowA * 128 + (kb ^ ((rowA & 7) << 4));
      int rowB = wc * 64 + mi * 16 + l15;
      pb[ks][mi] = smem[0] + 16384 + rowB * 128 + (kb ^ ((rowB & 7) << 4));
    }
  }

  auto CMP = [&](int off) {
    bf16x8 av[2][4], bv[2][4];
#pragma unroll
    for (int ks = 0; ks < 2; ++ks)
#pragma unroll
      for (int mi = 0; mi < 4; ++mi) {
        av[ks][mi] = *(const bf16x8*)(pa[ks][mi] + off);
        bv[ks][mi] = *(const bf16x8*)(pb[ks][mi] + off);
      }
#pragma unroll
    for (int ks = 0; ks < 2; ++ks)
#pragma unroll
      for (int mi = 0; mi < 4; ++mi)
#pragma unroll
        for (int ni = 0; ni < 4; ++ni)
          acc[mi][ni] = mfma16(av[ks][mi], bv[ks][ni], acc[mi][ni]);
  };

  STG(0, 0);
#pragma unroll
  for (int kt = 0; kt < 12; ++kt) {
    int cur = kt & 1;
    if (kt < 11) {
      STG(cur ^ 1, kt + 1);
      VMCNT(8);          // waits only on tile-kt's 8 loads; prefetch stays in flight
    } else {
      VMCNT(0);
    }
    SBAR();
    SCHED_FENCE();
    CMP(cur * 32768);
    SCHED_FENCE();
    if (kt < 11) SBAR();  // all waves done reading buf `cur` before it is re-staged
  }

#pragma unroll
  for (int mi = 0; mi < 4; ++mi) {
#pragma unroll
    for (int ni = 0; ni < 4; ++ni) {
      int col = n0 + wc * 64 + ni * 16 + l15;
      float bvs = bias[col];
#pragma unroll
      for (int j = 0; j < 4; ++j) {
        int row = m0 + wr * 64 + mi * 16 + g * 4 + j;
        float val = acc[mi][ni][j] + bvs;
        if constexpr (EPI == 0) {
          out[(size_t)row * Nw + col] = val;
        } else {
          int bI = row >> 10, n = row & 1023;
          int typ = col / 768, within = col % 768;
          int h = within >> 6, d = within & 63;
          int bh = bI * 12 + h;
          unsigned short bf = f2bf(val);
          unsigned short* dst = (typ == 0) ? Qb : (typ == 1) ? Kb : Vb;
          dst[((size_t)bh * 1024 + n) * 64 + d] = bf;
        }
      }
    }
  }
}

// ---------------- fused flash attention (swapped QK^T) ----------------
// 1D grid 768, XCD-chunked: all 8 n-blocks of a bh land on one XCD so K/V
// re-reads hit that XCD's L2. 4 waves x 32 q-rows. Counted-vmcnt pipeline.
__global__ __launch_bounds__(256, 3) void k_attn(
    const unsigned short* __restrict__ Q, const unsigned short* __restrict__ K,
    const unsigned short* __restrict__ Vt, unsigned short* __restrict__ Oa) {
  __shared__ char smem[49152];
  char* Ks = smem;           // 2 x 8192 (K dbuf); Vs = Ks + 16384 (2 x 8192)
  char* Ps = smem + 32768;   // 4 waves x 4096
  int t = threadIdx.x, w = t >> 6, lane = t & 63;
  int g = lane >> 4, l15 = lane & 15;

  int fb = blockIdx.x;
  int bh = (fb & 7) * 12 + ((fb >> 3) % 12);  // 12 bh per XCD
  int n0 = (fb / 96) * 128;
  int bI = bh / 12, h = bh % 12;
  char* Pw = Ps + w * 4096;

  // Q as B-fragments (registers for whole kernel)
  bf16x8 qf[2][2];
  {
    const char* qbase = (const char*)Q + ((size_t)bh * 1024 + n0 + w * 32 + l15) * 128 + g * 16;
    qf[0][0] = *(const bf16x8*)(qbase);
    qf[0][1] = *(const bf16x8*)(qbase + 64);
    qf[1][0] = *(const bf16x8*)(qbase + 16 * 128);
    qf[1][1] = *(const bf16x8*)(qbase + 16 * 128 + 64);
  }

  f32x4 acc[2][4] = {};
  float mrun[2] = {-INFINITY, -INFINITY};
  float lrun[2] = {0.f, 0.f};

  // hoisted LDS read pointers (buffer 0); buf1 via +8192, V via +16384
  const char* pK[2][4];
#pragma unroll
  for (int ks = 0; ks < 2; ++ks)
#pragma unroll
    for (int ff = 0; ff < 4; ++ff) {
      int row = ff * 16 + l15;
      pK[ks][ff] = Ks + row * 128 + ((ks * 64 + g * 16) ^ ((row & 7) << 4));
    }
  char* pPw[2][4];
  const char* pPr[2][2];
#pragma unroll
  for (int q = 0; q < 2; ++q) {
    int prow = q * 16 + l15, swz = (l15 & 7) << 4;
#pragma unroll
    for (int ff = 0; ff < 4; ++ff) pPw[q][ff] = Pw + prow * 128 + ((ff * 32 + g * 8) ^ swz);
#pragma unroll
    for (int ks = 0; ks < 2; ++ks) pPr[q][ks] = Pw + prow * 128 + ((ks * 64 + g * 16) ^ swz);
  }

  // staging pointers
  int o0 = t * 16, o1 = t * 16 + 4096;
  int r0 = o0 >> 7, r1 = o1 >> 7;
  int sb0 = (o0 & 127) ^ ((r0 & 7) << 4);
  int sb1 = (o1 & 127) ^ ((r1 & 7) << 4);
  const char* KgA = (const char*)K + (size_t)bh * 131072 + (size_t)r0 * 128 + sb0;
  const char* KgB = (const char*)K + (size_t)bh * 131072 + (size_t)r1 * 128 + sb1;
  const char* VgA = (const char*)Vt + (size_t)bh * 131072 + (size_t)r0 * 2048 + sb0;
  const char* VgB = (const char*)Vt + (size_t)bh * 131072 + (size_t)r1 * 2048 + sb1;

  auto STG = [&](int buf, int mt) {
    char* Kd = Ks + buf * 8192;
    char* Vd = Ks + 16384 + buf * 8192;
    gl_lds16(KgA + (size_t)mt * 8192, Kd + w * 1024);
    gl_lds16(KgB + (size_t)mt * 8192, Kd + 4096 + w * 1024);
    gl_lds16(VgA + (size_t)mt * 128, Vd + w * 1024);
    gl_lds16(VgB + (size_t)mt * 128, Vd + 4096 + w * 1024);
  };

  auto TILE = [&](int off) {
    // S^T = K Q^T : lane holds S[q = qf*16 + l15][kv = f*16 + g*4 + j]
    f32x4 s[4][2] = {};
#pragma unroll
    for (int ks = 0; ks < 2; ++ks)
#pragma unroll
      for (int ff = 0; ff < 4; ++ff) {
        bf16x8 kv = *(const bf16x8*)(pK[ks][ff] + off);
        s[ff][0] = mfma16(kv, qf[0][ks], s[ff][0]);
        s[ff][1] = mfma16(kv, qf[1][ks], s[ff][1]);
      }

    float pmax[2];
#pragma unroll
    for (int q = 0; q < 2; ++q) {
      float a0 = fmaxf(fmaxf(s[0][q][0], s[0][q][1]), fmaxf(s[0][q][2], s[0][q][3]));
      float a1 = fmaxf(fmaxf(s[1][q][0], s[1][q][1]), fmaxf(s[1][q][2], s[1][q][3]));
      float a2 = fmaxf(fmaxf(s[2][q][0], s[2][q][1]), fmaxf(s[2][q][2], s[2][q][3]));
      float a3 = fmaxf(fmaxf(s[3][q][0], s[3][q][1]), fmaxf(s[3][q][2], s[3][q][3]));
      float pm = fmaxf(fmaxf(a0, a1), fmaxf(a2, a3));
      pm = fmaxf(pm, __shfl_xor(pm, 16, 64));
      pm = fmaxf(pm, __shfl_xor(pm, 32, 64));
      pmax[q] = pm;
    }

    bool upd = (pmax[0] > mrun[0] + THRRAW) || (pmax[1] > mrun[1] + THRRAW);
    if (__any(upd)) {
#pragma unroll
      for (int q = 0; q < 2; ++q) {
        float mnew = fmaxf(mrun[q], pmax[q]);
        float alpha = __builtin_amdgcn_exp2f((mrun[q] - mnew) * CL2F);
        mrun[q] = mnew;
        lrun[q] *= alpha;
#pragma unroll
        for (int j = 0; j < 4; ++j) {
          float aj = __shfl(alpha, g * 4 + j, 64);
          acc[q][0][j] *= aj; acc[q][1][j] *= aj;
          acc[q][2][j] *= aj; acc[q][3][j] *= aj;
        }
      }
    }

#pragma unroll
    for (int q = 0; q < 2; ++q) {
      float nm = -mrun[q] * CL2F;
      float rs = 0.f;
#pragma unroll
      for (int ff = 0; ff < 4; ++ff) {
        float p0 = __builtin_amdgcn_exp2f(fmaf(s[ff][q][0], CL2F, nm));
        float p1 = __builtin_amdgcn_exp2f(fmaf(s[ff][q][1], CL2F, nm));
        float p2 = __builtin_amdgcn_exp2f(fmaf(s[ff][q][2], CL2F, nm));
        float p3 = __builtin_amdgcn_exp2f(fmaf(s[ff][q][3], CL2F, nm));
        rs += (p0 + p1) + (p2 + p3);
        uint2 pk;
        pk.x = cvtpk(p0, p1);
        pk.y = cvtpk(p2, p3);
        *(uint2*)(pPw[q][ff]) = pk;
      }
      rs += __shfl_xor(rs, 16, 64);
      rs += __shfl_xor(rs, 32, 64);
      lrun[q] += rs;
    }

    // O += P V
#pragma unroll
    for (int ks = 0; ks < 2; ++ks) {
      bf16x8 pa0 = *(const bf16x8*)(pPr[0][ks]);
      bf16x8 pa1 = *(const bf16x8*)(pPr[1][ks]);
#pragma unroll
      for (int fd = 0; fd < 4; ++fd) {
        bf16x8 vv = *(const bf16x8*)(pK[ks][fd] + 16384 + off);
        acc[0][fd] = mfma16(pa0, vv, acc[0][fd]);
        acc[1][fd] = mfma16(pa1, vv, acc[1][fd]);
      }
    }
  };

  STG(0, 0);
  for (int mt2 = 0; mt2 < 8; ++mt2) {
    // tile 2*mt2 from buf0
    STG(1, 2 * mt2 + 1);
    VMCNT(4);
    SBAR();
    SCHED_FENCE();
    TILE(0);
    SCHED_FENCE();
    SBAR();
    // tile 2*mt2+1 from buf1
    if (mt2 < 7) {
      STG(0, 2 * mt2 + 2);
      VMCNT(4);
    } else {
      VMCNT(0);
    }
    SBAR();
    SCHED_FENCE();
    TILE(8192);
    SCHED_FENCE();
    if (mt2 < 7) SBAR();
  }

  // epilogue: out[b][n][h*64+d] bf16, rows q' = q*16 + g*4 + j
#pragma unroll
  for (int q = 0; q < 2; ++q) {
#pragma unroll
    for (int j = 0; j < 4; ++j) {
      float lv = __shfl(lrun[q], g * 4 + j, 64);
      float inv = 1.0f / lv;
      int n = n0 + w * 32 + q * 16 + g * 4 + j;
      size_t rowb = ((size_t)bI * 1024 + n) * 768 + h * 64;
#pragma unroll
      for (int fd = 0; fd < 4; ++fd)
        Oa[rowb + fd * 16 + l15] = (unsigned short)(cvtpk(acc[q][fd][j] * inv, 0.f) & 0xffffu);
    }
  }
}

// ---------------------------------------------------------------------
extern "C" void kernel_launch(void* const* d_in, const int* in_sizes, int n_in,
                              void* d_out, int out_size, void* d_ws, size_t ws_size,
                              hipStream_t stream) {
  const float* x = (const float*)d_in[0];
  const float* Wqkv = (const float*)d_in[1];
  const float* bqkv = (const float*)d_in[2];
  const float* Wproj = (const float*)d_in[3];
  const float* bproj = (const float*)d_in[4];
  float* out = (float*)d_out;

  char* ws = (char*)d_ws;
  unsigned short* xb  = (unsigned short*)(ws);                      // 12,582,912 B
  unsigned short* wqt = (unsigned short*)(ws + 12582912);           //  3,538,944 B
  unsigned short* wpt = (unsigned short*)(ws + 16121856);           //  1,179,648 B
  unsigned short* Qb  = (unsigned short*)(ws + 17301504);           // 12,582,912 B
  unsigned short* Kb  = (unsigned short*)(ws + 29884416);           // 12,582,912 B
  unsigned short* Vtb = (unsigned short*)(ws + 42467328);           // 12,582,912 B
  unsigned short* Oa  = (unsigned short*)(ws + 55050240);           // 12,582,912 B
  unsigned short* Vb  = Oa;  // V row-layout aliases Oa slot (dead before attn writes Oa)

  k_cvt_x<<<dim3(6144), dim3(256), 0, stream>>>(x, xb, (Bb * Nn_ * Cc_) / 4);
  k_transpose<768, 2304><<<dim3(36, 12), dim3(256), 0, stream>>>(Wqkv, wqt);
  k_transpose<768, 768><<<dim3(12, 12), dim3(256), 0, stream>>>(Wproj, wpt);
  k_gemm<1><<<dim3(64, 18), dim3(256), 0, stream>>>(xb, wqt, bqkv, nullptr, Qb, Kb, Vb,
                                                    8192, 2304);
  k_transpose_v<<<dim3(16, 96), dim3(256), 0, stream>>>(Vb, Vtb);
  k_attn<<<dim3(768), dim3(256), 0, stream>>>(Qb, Kb, Vtb, Oa);
  k_gemm<0><<<dim3(64, 6), dim3(256), 0, stream>>>(Oa, wpt, bproj, out, nullptr, nullptr, nullptr,
                                                   8192, 768);
}